// Round 7
// baseline (204.047 us; speedup 1.0000x reference)
//
#include <hip/hip_runtime.h>
#include <hip/hip_cooperative_groups.h>

namespace cg = cooperative_groups;

#define NB 32
#define NN 256
#define DD 64
#define GG 4            // node-groups per batch
#define NPB 64          // nodes per block
#define NBLK (NB * GG)  // 128 blocks

// R7: single cooperative kernel (128 blocks x 512 threads, grid.sync between
// phases). vs R6's 4-kernel pipeline: ti stays in REGISTERS across phases
// (R6 round-tripped 2MB through ws twice), 3 launch boundaries gone. Only
// the per-group reduction partials (~100KB) cross blocks via ws. Mapping
// unchanged from R6 (proven): lane = node, wave = 8-dim slice (wave-uniform
// -> weight reads are s_load), node reductions = 64-lane shfl_xor butterfly.
// Harness floor: the 0xAA poison of the 256MiB ws costs ~40us/iter at 84%
// HBM peak (fillBufferAligned in R6 counters) — not addressable from here.
//
// ws layout (floats): PMAX1@0 PMIN1@8192 PMAX2@16384 PMIN2@24576
//                     PSUM@32768 PMXP@40960   (48K floats = 192 KB)

__global__ __launch_bounds__(512, 1) void pnet_coop(
    const float* __restrict__ x,
    const float* __restrict__ W1,  const float* __restrict__ b1,
    const float* __restrict__ g1,  const float* __restrict__ beta1,
    const float* __restrict__ We1, const float* __restrict__ be1,
    const float* __restrict__ ge1, const float* __restrict__ bte1,
    const float* __restrict__ We2, const float* __restrict__ be2,
    const float* __restrict__ ge2, const float* __restrict__ bte2,
    const float* __restrict__ Wg1, const float* __restrict__ bg1,
    const float* __restrict__ Wg2, const float* __restrict__ bg2,
    float* __restrict__ PM, float* __restrict__ out)
{
    cg::grid_group grid = cg::this_grid();

    __shared__ float Hs[NPB * 65];   // 16.6 KB: h tile (stride 65: 2-way alias only)
    __shared__ float XG[2 * DD];
    __shared__ float HID[DD];

    float* PMAX1 = PM;
    float* PMIN1 = PM + 8192;
    float* PMAX2 = PM + 16384;
    float* PMIN2 = PM + 24576;
    float* PSUM  = PM + 32768;
    float* PMXP  = PM + 40960;

    const int bid = blockIdx.x;
    const int b   = bid >> 2;
    const int g   = bid & 3;
    const int l   = threadIdx.x & 63;                                 // node lane
    const int w   = __builtin_amdgcn_readfirstlane(threadIdx.x >> 6); // wave 0..7
    const int n   = g * NPB + l;
    const int d0  = w * 8;                                            // dim slice

    // ================= P1: layer1 + conv1 matvec + tj1 partial reduce =================
    {
        float4 xv = *(const float4*)(x + ((size_t)b * NN + n) * 4);
        float a[8];
#pragma unroll
        for (int j = 0; j < 8; ++j) a[j] = b1[d0 + j];
#pragma unroll
        for (int j = 0; j < 8; ++j) a[j] = fmaf(xv.x, W1[0 * DD + d0 + j], a[j]);
#pragma unroll
        for (int j = 0; j < 8; ++j) a[j] = fmaf(xv.y, W1[1 * DD + d0 + j], a[j]);
#pragma unroll
        for (int j = 0; j < 8; ++j) a[j] = fmaf(xv.z, W1[2 * DD + d0 + j], a[j]);
#pragma unroll
        for (int j = 0; j < 8; ++j) a[j] = fmaf(xv.w, W1[3 * DD + d0 + j], a[j]);
#pragma unroll
        for (int j = 0; j < 8; ++j)
            Hs[l * 65 + d0 + j] = g1[d0 + j] * fmaxf(a[j], 0.f) + beta1[d0 + j];
    }
    __syncthreads();

    float ti1[8];
    {
        float tj[8];
#pragma unroll
        for (int j = 0; j < 8; ++j) { ti1[j] = 0.f; tj[j] = 0.f; }
#pragma unroll
        for (int k = 0; k < DD; ++k) {
            const float hk = Hs[l * 65 + k];
            const float* wi = We1 + k * DD + d0;          // wave-uniform -> s_load
            const float* wj = We1 + (DD + k) * DD + d0;
#pragma unroll
            for (int j = 0; j < 8; ++j) {
                ti1[j] = fmaf(hk, wi[j], ti1[j]);
                tj[j]  = fmaf(hk, wj[j], tj[j]);
            }
        }
        float mx[8], mn[8];
#pragma unroll
        for (int j = 0; j < 8; ++j) { mx[j] = tj[j]; mn[j] = tj[j]; }
#pragma unroll
        for (int m = 1; m < 64; m <<= 1) {
#pragma unroll
            for (int j = 0; j < 8; ++j) {
                mx[j] = fmaxf(mx[j], __shfl_xor(mx[j], m, 64));
                mn[j] = fminf(mn[j], __shfl_xor(mn[j], m, 64));
            }
        }
        float smx = mx[0], smn = mn[0];
#pragma unroll
        for (int j = 1; j < 8; ++j) {
            smx = (l == j) ? mx[j] : smx;
            smn = (l == j) ? mn[j] : smn;
        }
        if (l < 8) {
            PMAX1[(b * GG + g) * DD + d0 + l] = smx;
            PMIN1[(b * GG + g) * DD + d0 + l] = smn;
        }
    }
    grid.sync();

    // ================= P2: epilogue1 + conv2 matvec + tj2 partial reduce =================
    float ti2[8];
    {
        float rmax[8], rmin[8];
#pragma unroll
        for (int j = 0; j < 8; ++j) {
            rmax[j] = fmaxf(fmaxf(PMAX1[(b * GG + 0) * DD + d0 + j],
                                  PMAX1[(b * GG + 1) * DD + d0 + j]),
                            fmaxf(PMAX1[(b * GG + 2) * DD + d0 + j],
                                  PMAX1[(b * GG + 3) * DD + d0 + j]));
            rmin[j] = fminf(fminf(PMIN1[(b * GG + 0) * DD + d0 + j],
                                  PMIN1[(b * GG + 1) * DD + d0 + j]),
                            fminf(PMIN1[(b * GG + 2) * DD + d0 + j],
                                  PMIN1[(b * GG + 3) * DD + d0 + j]));
        }
        __syncthreads();   // all waves done reading Hs (h_prev) before overwrite
#pragma unroll
        for (int j = 0; j < 8; ++j) {
            float gv = ge1[d0 + j];
            float sv = ti1[j] + (gv >= 0.f ? rmax[j] : rmin[j]) + be1[d0 + j];
            Hs[l * 65 + d0 + j] = gv * fmaxf(sv, 0.f) + bte1[d0 + j];
        }
        __syncthreads();

        float tj[8];
#pragma unroll
        for (int j = 0; j < 8; ++j) { ti2[j] = 0.f; tj[j] = 0.f; }
#pragma unroll
        for (int k = 0; k < DD; ++k) {
            const float hk = Hs[l * 65 + k];
            const float* wi = We2 + k * DD + d0;
            const float* wj = We2 + (DD + k) * DD + d0;
#pragma unroll
            for (int j = 0; j < 8; ++j) {
                ti2[j] = fmaf(hk, wi[j], ti2[j]);
                tj[j]  = fmaf(hk, wj[j], tj[j]);
            }
        }
        float mx[8], mn[8];
#pragma unroll
        for (int j = 0; j < 8; ++j) { mx[j] = tj[j]; mn[j] = tj[j]; }
#pragma unroll
        for (int m = 1; m < 64; m <<= 1) {
#pragma unroll
            for (int j = 0; j < 8; ++j) {
                mx[j] = fmaxf(mx[j], __shfl_xor(mx[j], m, 64));
                mn[j] = fminf(mn[j], __shfl_xor(mn[j], m, 64));
            }
        }
        float smx = mx[0], smn = mn[0];
#pragma unroll
        for (int j = 1; j < 8; ++j) {
            smx = (l == j) ? mx[j] : smx;
            smn = (l == j) ? mn[j] : smn;
        }
        if (l < 8) {
            PMAX2[(b * GG + g) * DD + d0 + l] = smx;
            PMIN2[(b * GG + g) * DD + d0 + l] = smn;
        }
    }
    grid.sync();

    // ================= P3: epilogue2 + pooling partials =================
    {
        float rmax[8], rmin[8];
#pragma unroll
        for (int j = 0; j < 8; ++j) {
            rmax[j] = fmaxf(fmaxf(PMAX2[(b * GG + 0) * DD + d0 + j],
                                  PMAX2[(b * GG + 1) * DD + d0 + j]),
                            fmaxf(PMAX2[(b * GG + 2) * DD + d0 + j],
                                  PMAX2[(b * GG + 3) * DD + d0 + j]));
            rmin[j] = fminf(fminf(PMIN2[(b * GG + 0) * DD + d0 + j],
                                  PMIN2[(b * GG + 1) * DD + d0 + j]),
                            fminf(PMIN2[(b * GG + 2) * DD + d0 + j],
                                  PMIN2[(b * GG + 3) * DD + d0 + j]));
        }
        float hv[8];
#pragma unroll
        for (int j = 0; j < 8; ++j) {
            float gv = ge2[d0 + j];
            float sv = ti2[j] + (gv >= 0.f ? rmax[j] : rmin[j]) + be2[d0 + j];
            hv[j] = gv * fmaxf(sv, 0.f) + bte2[d0 + j];
        }
        float sm[8], mx[8];
#pragma unroll
        for (int j = 0; j < 8; ++j) { sm[j] = hv[j]; mx[j] = hv[j]; }
#pragma unroll
        for (int m = 1; m < 64; m <<= 1) {
#pragma unroll
            for (int j = 0; j < 8; ++j) {
                sm[j] += __shfl_xor(sm[j], m, 64);
                mx[j] = fmaxf(mx[j], __shfl_xor(mx[j], m, 64));
            }
        }
        float ssm = sm[0], smx = mx[0];
#pragma unroll
        for (int j = 1; j < 8; ++j) {
            ssm = (l == j) ? sm[j] : ssm;
            smx = (l == j) ? mx[j] : smx;
        }
        if (l < 8) {
            PSUM[(b * GG + g) * DD + d0 + l] = ssm;
            PMXP[(b * GG + g) * DD + d0 + l] = smx;
        }
    }
    grid.sync();

    // ================= P4: pooling finalize + head MLP (g==0 blocks only) =================
    if (g == 0) {
        const int t = threadIdx.x;
        if (t < 64) {
            float s = PSUM[(b * GG + 0) * DD + t] + PSUM[(b * GG + 1) * DD + t]
                    + PSUM[(b * GG + 2) * DD + t] + PSUM[(b * GG + 3) * DD + t];
            XG[t] = s * (1.f / 256.f);
        } else if (t < 128) {
            int d = t - 64;
            XG[64 + d] = fmaxf(fmaxf(PMXP[(b * GG + 0) * DD + d], PMXP[(b * GG + 1) * DD + d]),
                               fmaxf(PMXP[(b * GG + 2) * DD + d], PMXP[(b * GG + 3) * DD + d]));
        }
        __syncthreads();
        if (t < 64) {
            float a = bg1[t];
#pragma unroll
            for (int k = 0; k < 2 * DD; ++k) a = fmaf(XG[k], Wg1[k * DD + t], a);
            HID[t] = fmaxf(a, 0.f);
        }
        __syncthreads();
        if (t < 2) {
            float o = bg2[t];
#pragma unroll
            for (int j = 0; j < DD; ++j) o = fmaf(HID[j], Wg2[j * 2 + t], o);
            out[b * 2 + t] = o;
        }
    }
}

extern "C" void kernel_launch(void* const* d_in, const int* in_sizes, int n_in,
                              void* d_out, int out_size, void* d_ws, size_t ws_size,
                              hipStream_t stream) {
    const float* x     = (const float*)d_in[0];
    const float* W1    = (const float*)d_in[1];
    const float* b1    = (const float*)d_in[2];
    const float* g1    = (const float*)d_in[3];
    const float* beta1 = (const float*)d_in[4];
    const float* We1   = (const float*)d_in[5];
    const float* be1   = (const float*)d_in[6];
    const float* ge1   = (const float*)d_in[7];
    const float* bte1  = (const float*)d_in[8];
    const float* We2   = (const float*)d_in[9];
    const float* be2   = (const float*)d_in[10];
    const float* ge2   = (const float*)d_in[11];
    const float* bte2  = (const float*)d_in[12];
    const float* Wg1   = (const float*)d_in[13];
    const float* bg1   = (const float*)d_in[14];
    const float* Wg2   = (const float*)d_in[15];
    const float* bg2   = (const float*)d_in[16];
    float* PM  = (float*)d_ws;
    float* out = (float*)d_out;

    void* args[] = {
        (void*)&x, (void*)&W1, (void*)&b1, (void*)&g1, (void*)&beta1,
        (void*)&We1, (void*)&be1, (void*)&ge1, (void*)&bte1,
        (void*)&We2, (void*)&be2, (void*)&ge2, (void*)&bte2,
        (void*)&Wg1, (void*)&bg1, (void*)&Wg2, (void*)&bg2,
        (void*)&PM, (void*)&out
    };
    hipLaunchCooperativeKernel((void*)pnet_coop, dim3(NBLK), dim3(512),
                               args, 0, stream);
}

// Round 8
// 123.215 us; speedup vs baseline: 1.6560x; 1.6560x over previous
//
#include <hip/hip_runtime.h>

#define NB 32
#define NN 256
#define DD 64
#define GG 4            // node-groups per batch
#define NPB 64          // nodes per block (conv kernels)

// R8: R6 pipeline (stream-ordered kernel boundaries BEAT cooperative
// grid.sync on MI355X: R7's 3 grid.syncs cost ~25us EACH — cross-XCD L2
// flush + 128-block rendezvous) with k_pool+k_head merged into one kernel.
// 3 dispatches total. Addressable time is only ~43us of 121 (the 0xAA
// poison of the 256MiB ws is a fixed ~40us harness cost at 84% HBM peak).
//
// ws layout (floats):
//   TI    @ 0        NB*NN*DD = 524288
//   PMAX1 @ 524288   NB*GG*DD = 8192
//   PMIN1 @ 532480   8192
//   PMAX2 @ 540672   8192
//   PMIN2 @ 548864   8192      (total 557056 floats = 2.23 MB)

__global__ __launch_bounds__(512) void k_conv1(
    const float* __restrict__ x,
    const float* __restrict__ W1,  const float* __restrict__ b1,
    const float* __restrict__ g1,  const float* __restrict__ beta1,
    const float* __restrict__ We1,
    float* __restrict__ TI, float* __restrict__ PMAX, float* __restrict__ PMIN)
{
    __shared__ float Hs[NPB * 65];   // stride 65 -> 2-way bank alias only (free)
    const int b  = blockIdx.x >> 2;
    const int g  = blockIdx.x & 3;
    const int l  = threadIdx.x & 63;                                // node lane
    const int w  = __builtin_amdgcn_readfirstlane(threadIdx.x >> 6); // wave 0..7 (SGPR)
    const int n  = g * NPB + l;
    const int d0 = w * 8;                                           // wave's dim slice

    // ---- layer 1: h[n, d0..d0+8] = bn(relu(x @ W1 + b1)) ----
    {
        float4 xv = *(const float4*)(x + ((size_t)b * NN + n) * 4);
        float a[8];
#pragma unroll
        for (int j = 0; j < 8; ++j) a[j] = b1[d0 + j];
#pragma unroll
        for (int j = 0; j < 8; ++j) a[j] = fmaf(xv.x, W1[0 * DD + d0 + j], a[j]);
#pragma unroll
        for (int j = 0; j < 8; ++j) a[j] = fmaf(xv.y, W1[1 * DD + d0 + j], a[j]);
#pragma unroll
        for (int j = 0; j < 8; ++j) a[j] = fmaf(xv.z, W1[2 * DD + d0 + j], a[j]);
#pragma unroll
        for (int j = 0; j < 8; ++j) a[j] = fmaf(xv.w, W1[3 * DD + d0 + j], a[j]);
#pragma unroll
        for (int j = 0; j < 8; ++j)
            Hs[l * 65 + d0 + j] = g1[d0 + j] * fmaxf(a[j], 0.f) + beta1[d0 + j];
    }
    __syncthreads();

    // ---- conv1 matvec: ti/tj[d0..d0+8] for node n; weights via s_load ----
    float ti[8], tj[8];
#pragma unroll
    for (int j = 0; j < 8; ++j) { ti[j] = 0.f; tj[j] = 0.f; }
#pragma unroll
    for (int k = 0; k < DD; ++k) {
        const float hk = Hs[l * 65 + k];
        const float* wi = We1 + k * DD + d0;          // wave-uniform address
        const float* wj = We1 + (DD + k) * DD + d0;   // wave-uniform address
#pragma unroll
        for (int j = 0; j < 8; ++j) {
            ti[j] = fmaf(hk, wi[j], ti[j]);
            tj[j] = fmaf(hk, wj[j], tj[j]);
        }
    }
    {
        float* o = TI + ((size_t)(b * NN + n)) * DD + d0;
        *(float4*)(o)     = make_float4(ti[0], ti[1], ti[2], ti[3]);
        *(float4*)(o + 4) = make_float4(ti[4], ti[5], ti[6], ti[7]);
    }
    // butterfly max/min of tj over the 64 nodes (lanes)
    float mx[8], mn[8];
#pragma unroll
    for (int j = 0; j < 8; ++j) { mx[j] = tj[j]; mn[j] = tj[j]; }
#pragma unroll
    for (int m = 1; m < 64; m <<= 1) {
#pragma unroll
        for (int j = 0; j < 8; ++j) {
            mx[j] = fmaxf(mx[j], __shfl_xor(mx[j], m, 64));
            mn[j] = fminf(mn[j], __shfl_xor(mn[j], m, 64));
        }
    }
    float smx = mx[0], smn = mn[0];
#pragma unroll
    for (int j = 1; j < 8; ++j) {
        smx = (l == j) ? mx[j] : smx;
        smn = (l == j) ? mn[j] : smn;
    }
    if (l < 8) {
        PMAX[(b * GG + g) * DD + d0 + l] = smx;
        PMIN[(b * GG + g) * DD + d0 + l] = smn;
    }
}

// epilogue of conv1 (partials combined from ws) + conv2 matvec
__global__ __launch_bounds__(512) void k_conv2(
    const float* __restrict__ PMAXin, const float* __restrict__ PMINin,
    const float* __restrict__ beP, const float* __restrict__ geP,
    const float* __restrict__ bteP,
    const float* __restrict__ We,
    float* __restrict__ TI, float* __restrict__ PMAX, float* __restrict__ PMIN)
{
    __shared__ float Hs[NPB * 65];
    const int b  = blockIdx.x >> 2;
    const int g  = blockIdx.x & 3;
    const int l  = threadIdx.x & 63;
    const int w  = __builtin_amdgcn_readfirstlane(threadIdx.x >> 6);
    const int n  = g * NPB + l;
    const int d0 = w * 8;

    float rmax[8], rmin[8];
#pragma unroll
    for (int j = 0; j < 8; ++j) {
        rmax[j] = fmaxf(fmaxf(PMAXin[(b * GG + 0) * DD + d0 + j],
                              PMAXin[(b * GG + 1) * DD + d0 + j]),
                        fmaxf(PMAXin[(b * GG + 2) * DD + d0 + j],
                              PMAXin[(b * GG + 3) * DD + d0 + j]));
        rmin[j] = fminf(fminf(PMINin[(b * GG + 0) * DD + d0 + j],
                              PMINin[(b * GG + 1) * DD + d0 + j]),
                        fminf(PMINin[(b * GG + 2) * DD + d0 + j],
                              PMINin[(b * GG + 3) * DD + d0 + j]));
    }
    {
        const float* tip = TI + ((size_t)(b * NN + n)) * DD + d0;
        float4 t0 = *(const float4*)tip;
        float4 t1 = *(const float4*)(tip + 4);
        float tiv[8] = {t0.x, t0.y, t0.z, t0.w, t1.x, t1.y, t1.z, t1.w};
#pragma unroll
        for (int j = 0; j < 8; ++j) {
            float gv = geP[d0 + j];
            float sv = tiv[j] + (gv >= 0.f ? rmax[j] : rmin[j]) + beP[d0 + j];
            Hs[l * 65 + d0 + j] = gv * fmaxf(sv, 0.f) + bteP[d0 + j];
        }
    }
    __syncthreads();

    float ti[8], tj[8];
#pragma unroll
    for (int j = 0; j < 8; ++j) { ti[j] = 0.f; tj[j] = 0.f; }
#pragma unroll
    for (int k = 0; k < DD; ++k) {
        const float hk = Hs[l * 65 + k];
        const float* wi = We + k * DD + d0;
        const float* wj = We + (DD + k) * DD + d0;
#pragma unroll
        for (int j = 0; j < 8; ++j) {
            ti[j] = fmaf(hk, wi[j], ti[j]);
            tj[j] = fmaf(hk, wj[j], tj[j]);
        }
    }
    {
        float* o = TI + ((size_t)(b * NN + n)) * DD + d0;  // in-place: same thread read it
        *(float4*)(o)     = make_float4(ti[0], ti[1], ti[2], ti[3]);
        *(float4*)(o + 4) = make_float4(ti[4], ti[5], ti[6], ti[7]);
    }
    float mx[8], mn[8];
#pragma unroll
    for (int j = 0; j < 8; ++j) { mx[j] = tj[j]; mn[j] = tj[j]; }
#pragma unroll
    for (int m = 1; m < 64; m <<= 1) {
#pragma unroll
        for (int j = 0; j < 8; ++j) {
            mx[j] = fmaxf(mx[j], __shfl_xor(mx[j], m, 64));
            mn[j] = fminf(mn[j], __shfl_xor(mn[j], m, 64));
        }
    }
    float smx = mx[0], smn = mn[0];
#pragma unroll
    for (int j = 1; j < 8; ++j) {
        smx = (l == j) ? mx[j] : smx;
        smn = (l == j) ? mn[j] : smn;
    }
    if (l < 8) {
        PMAX[(b * GG + g) * DD + d0 + l] = smx;
        PMIN[(b * GG + g) * DD + d0 + l] = smn;
    }
}

// conv2 epilogue + full pooling + head MLP, one block per batch.
// 512 threads: waves 0-3 = dim-slice 0 (dims 0..31), waves 4-7 = slice 1
// (dims 32..63); node n = (wave&3)*64 + lane.
__global__ __launch_bounds__(512, 1) void k_poolhead(
    const float* __restrict__ PMAXin, const float* __restrict__ PMINin,
    const float* __restrict__ beP, const float* __restrict__ geP,
    const float* __restrict__ bteP,
    const float* __restrict__ TI,
    const float* __restrict__ Wg1, const float* __restrict__ bg1,
    const float* __restrict__ Wg2, const float* __restrict__ bg2,
    float* __restrict__ out)
{
    __shared__ float TT[2 * NN * 33];  // 67.6 KB: [slice][node][dim&31], stride 33
    __shared__ float PA[8 * 64];       // pooling partial sums
    __shared__ float PB[8 * 64];       // pooling partial maxes
    __shared__ float XG[2 * DD];
    __shared__ float HID[DD];

    const int b  = blockIdx.x;
    const int t  = threadIdx.x;
    const int l  = t & 63;
    const int w  = __builtin_amdgcn_readfirstlane(t >> 6);   // wave 0..7
    const int s2 = w >> 2;                                   // dim slice 0/1 (uniform)
    const int n  = (w & 3) * 64 + l;                         // node
    const int d0 = s2 * 32;

    // combine conv2 partials for this wave's 32 dims (wave-uniform reads)
    float rmax[32], rmin[32];
#pragma unroll
    for (int j = 0; j < 32; ++j) {
        rmax[j] = fmaxf(fmaxf(PMAXin[(b * GG + 0) * DD + d0 + j],
                              PMAXin[(b * GG + 1) * DD + d0 + j]),
                        fmaxf(PMAXin[(b * GG + 2) * DD + d0 + j],
                              PMAXin[(b * GG + 3) * DD + d0 + j]));
        rmin[j] = fminf(fminf(PMINin[(b * GG + 0) * DD + d0 + j],
                              PMINin[(b * GG + 1) * DD + d0 + j]),
                        fminf(PMINin[(b * GG + 2) * DD + d0 + j],
                              PMINin[(b * GG + 3) * DD + d0 + j]));
    }

    // conv2 epilogue -> h values for (node n, dims d0..d0+32) -> LDS stage
    {
        const float* tip = TI + ((size_t)(b * NN + n)) * DD + d0;
        float* Tw = TT + (s2 * NN + n) * 33;
#pragma unroll
        for (int j4 = 0; j4 < 8; ++j4) {
            float4 tv = ((const float4*)tip)[j4];
            float tvv[4] = {tv.x, tv.y, tv.z, tv.w};
#pragma unroll
            for (int q = 0; q < 4; ++q) {
                int j = 4 * j4 + q;
                float gv = geP[d0 + j];
                float sv = tvv[q] + (gv >= 0.f ? rmax[j] : rmin[j]) + beP[d0 + j];
                Tw[j] = gv * fmaxf(sv, 0.f) + bteP[d0 + j];
            }
        }
    }
    __syncthreads();

    // pooling partials: thread t -> dim d = t&63, node group grp = t>>6 (32 nodes)
    {
        const int d   = t & 63;
        const int grp = t >> 6;
        const int ss  = d >> 5;
        const int jj  = d & 31;
        float sm = 0.f, mx = -3.402823466e+38f;
#pragma unroll
        for (int m = 0; m < 32; ++m) {
            float v = TT[(ss * NN + grp * 32 + m) * 33 + jj];
            sm += v;
            mx = fmaxf(mx, v);
        }
        PA[grp * 64 + d] = sm;
        PB[grp * 64 + d] = mx;
    }
    __syncthreads();
    if (t < 64) {
        float asum = PA[t], amax = PB[t];
#pragma unroll
        for (int q = 1; q < 8; ++q) {
            asum += PA[q * 64 + t];
            amax = fmaxf(amax, PB[q * 64 + t]);
        }
        XG[t]      = asum * (1.f / 256.f);
        XG[64 + t] = amax;
    }
    __syncthreads();

    // head MLP
    if (t < 64) {
        float a = bg1[t];
#pragma unroll
        for (int k = 0; k < 2 * DD; ++k) a = fmaf(XG[k], Wg1[k * DD + t], a);
        HID[t] = fmaxf(a, 0.f);
    }
    __syncthreads();
    if (t < 2) {
        float o = bg2[t];
#pragma unroll
        for (int j = 0; j < DD; ++j) o = fmaf(HID[j], Wg2[j * 2 + t], o);
        out[b * 2 + t] = o;
    }
}

extern "C" void kernel_launch(void* const* d_in, const int* in_sizes, int n_in,
                              void* d_out, int out_size, void* d_ws, size_t ws_size,
                              hipStream_t stream) {
    const float* x     = (const float*)d_in[0];
    const float* W1    = (const float*)d_in[1];
    const float* b1    = (const float*)d_in[2];
    const float* g1    = (const float*)d_in[3];
    const float* beta1 = (const float*)d_in[4];
    const float* We1   = (const float*)d_in[5];
    const float* be1   = (const float*)d_in[6];
    const float* ge1   = (const float*)d_in[7];
    const float* bte1  = (const float*)d_in[8];
    const float* We2   = (const float*)d_in[9];
    const float* be2   = (const float*)d_in[10];
    const float* ge2   = (const float*)d_in[11];
    const float* bte2  = (const float*)d_in[12];
    const float* Wg1   = (const float*)d_in[13];
    const float* bg1   = (const float*)d_in[14];
    const float* Wg2   = (const float*)d_in[15];
    const float* bg2   = (const float*)d_in[16];

    float* ws    = (float*)d_ws;
    float* TI    = ws;
    float* PMAX1 = ws + 524288;
    float* PMIN1 = ws + 532480;
    float* PMAX2 = ws + 540672;
    float* PMIN2 = ws + 548864;

    k_conv1<<<dim3(NB * GG), dim3(512), 0, stream>>>(
        x, W1, b1, g1, beta1, We1, TI, PMAX1, PMIN1);
    k_conv2<<<dim3(NB * GG), dim3(512), 0, stream>>>(
        PMAX1, PMIN1, be1, ge1, bte1, We2, TI, PMAX2, PMIN2);
    k_poolhead<<<dim3(NB), dim3(512), 0, stream>>>(
        PMAX2, PMIN2, be2, ge2, bte2, TI, Wg1, bg1, Wg2, bg2, (float*)d_out);
}